// Round 8
// baseline (429.737 us; speedup 1.0000x reference)
//
#include <hip/hip_runtime.h>

#define NNODES 100000
#define NEDGES 1600000
#define INDIM 128
#define OUTD 32
#define HEADS 4
#define EDIM 32
#define NET 8
#define NEG 0.2f
#define CAP 64           // per-node bucket capacity (Poisson(16): P(>64) ~ 1e-20)

typedef unsigned short u16;
typedef unsigned int u32;
typedef __attribute__((ext_vector_type(8))) short bf16x8;
typedef __attribute__((ext_vector_type(4))) float f32x4;

__device__ __forceinline__ float bf2f(u16 u){ return __uint_as_float(((u32)u) << 16); }
__device__ __forceinline__ u16 f2bf(float f){
  u32 x = __float_as_uint(f);
  return (u16)((x + 0x7fffu + ((x >> 16) & 1u)) >> 16);   // RNE
}

// ---------------------------------------------------------------------------
// k_prep: block 0 -> he_t;  blocks 1..128 -> Wt transpose+cast;  all -> zero cnt
// ---------------------------------------------------------------------------
__global__ void k_prep(const float* __restrict__ edge_emb, const float* __restrict__ Wr,
                       const float* __restrict__ a_e, const float* __restrict__ W,
                       const float* __restrict__ res_w,
                       float* __restrict__ he_t, u16* __restrict__ Wt,
                       int* __restrict__ cnt){
  const int b = blockIdx.x, tid = threadIdx.x;
  for (int i = b * 256 + tid; i < NNODES; i += gridDim.x * 256) cnt[i] = 0;

  if (b == 0){
    __shared__ float sc[NET * 128];
    for (int idx = tid; idx < NET * 128; idx += 256){
      int t = idx >> 7, o = idx & 127;
      float s = 0.f;
      #pragma unroll
      for (int e = 0; e < EDIM; ++e)
        s += edge_emb[t * EDIM + e] * Wr[t * EDIM * 128 + e * 128 + o];
      sc[idx] = s * a_e[o];
    }
    __syncthreads();
    if (tid < NET * HEADS){
      int t = tid >> 2, h = tid & 3;
      float s = 0.f;
      #pragma unroll
      for (int d = 0; d < EDIM; ++d) s += sc[t * 128 + h * EDIM + d];
      he_t[tid] = s;
    }
  } else {
    int idx = (b - 1) * 256 + tid;     // 128 blocks cover 256*128
    int n = idx >> 7, k = idx & 127;
    float v = (n < 128) ? W[k * 128 + n] : res_w[k * 128 + (n - 128)];
    Wt[idx] = f2bf(v);
  }
}

// ---------------------------------------------------------------------------
// k_scatter: bucket scatter rtp[c*CAP+pos] = row | etype<<17
// ---------------------------------------------------------------------------
__global__ void k_scatter(const int* __restrict__ row, const int* __restrict__ col,
                          const int* __restrict__ et, int* __restrict__ cnt,
                          int* __restrict__ rtp){
  int e = blockIdx.x * 256 + threadIdx.x;
  if (e >= NEDGES) return;
  int c = col[e];
  int pos = atomicAdd(&cnt[c], 1);
  if (pos < CAP) rtp[c * CAP + pos] = row[e] | (et[e] << 17);
}

// ---------------------------------------------------------------------------
// k_gemm2: 128 rows x 256 cols per block; 4 waves; wave = 2 m-tiles of 16.
// Wt staged in LDS in two 128-row phases (pitch 136 u16: 16B-aligned, 2-way
// bank spread = free). Phase 0 -> emb bf16 + h_l/h_r; phase 1 -> d_out fp32.
// ---------------------------------------------------------------------------
__global__ __launch_bounds__(256) void k_gemm2(
    const float* __restrict__ hmat, const u16* __restrict__ Wt,
    const float* __restrict__ res_b, const float* __restrict__ a_l,
    const float* __restrict__ a_r, u16* __restrict__ emb, float* __restrict__ outres,
    float* __restrict__ h_l, float* __restrict__ h_r){
  __shared__ u16 Wl[128 * 136];        // 34.8 KB
  const int tid = threadIdx.x;
  const int wid = tid >> 6, lane = tid & 63;
  const int m0 = blockIdx.x * 128 + wid * 32;
  const int mcol = lane & 15, quad = lane >> 4;

  // A fragments: 2 row-tiles x 4 k-steps, fp32 -> bf16 in-register
  bf16x8 A[2][4];
  #pragma unroll
  for (int mt = 0; mt < 2; ++mt){
    int r = m0 + mt * 16 + mcol;
    int rc = r < NNODES ? r : NNODES - 1;
    const float* hrow = &hmat[rc * 128 + quad * 8];
    #pragma unroll
    for (int ks = 0; ks < 4; ++ks){
      float4 a0 = *(const float4*)&hrow[ks * 32];
      float4 a1 = *(const float4*)&hrow[ks * 32 + 4];
      A[mt][ks][0] = (short)f2bf(a0.x); A[mt][ks][1] = (short)f2bf(a0.y);
      A[mt][ks][2] = (short)f2bf(a0.z); A[mt][ks][3] = (short)f2bf(a0.w);
      A[mt][ks][4] = (short)f2bf(a1.x); A[mt][ks][5] = (short)f2bf(a1.y);
      A[mt][ks][6] = (short)f2bf(a1.z); A[mt][ks][7] = (short)f2bf(a1.w);
    }
  }

  float pl[2][4] = {}, pr[2][4] = {};
  #pragma unroll
  for (int phase = 0; phase < 2; ++phase){
    if (phase) __syncthreads();
    // stage 128 rows of Wt (32 KB) -> LDS, 8 x 16B per thread
    #pragma unroll
    for (int j = 0; j < 8; ++j){
      int cid = tid + j * 256;          // 2048 chunks of ushort8
      int rowL = cid >> 4, k8 = cid & 15;
      *(uint4*)&Wl[rowL * 136 + k8 * 8] =
          *(const uint4*)&Wt[(phase * 128 + rowL) * 128 + k8 * 8];
    }
    __syncthreads();

    #pragma unroll
    for (int ntl = 0; ntl < 8; ++ntl){
      bf16x8 B[4];
      const u16* bp = &Wl[(ntl * 16 + mcol) * 136 + quad * 8];
      #pragma unroll
      for (int ks = 0; ks < 4; ++ks) B[ks] = *(const bf16x8*)&bp[ks * 32];

      f32x4 acc[2] = {{0.f,0.f,0.f,0.f},{0.f,0.f,0.f,0.f}};
      #pragma unroll
      for (int ks = 0; ks < 4; ++ks){
        acc[0] = __builtin_amdgcn_mfma_f32_16x16x32_bf16(A[0][ks], B[ks], acc[0], 0, 0, 0);
        acc[1] = __builtin_amdgcn_mfma_f32_16x16x32_bf16(A[1][ks], B[ks], acc[1], 0, 0, 0);
      }

      const int c = ntl * 16 + mcol;      // column within the 128-col phase
      if (phase == 0){
        float alc = a_l[c], arc = a_r[c];
        #pragma unroll
        for (int mt = 0; mt < 2; ++mt){
          #pragma unroll
          for (int reg = 0; reg < 4; ++reg){
            int rw = m0 + mt * 16 + quad * 4 + reg;
            if (rw < NNODES) emb[rw * 128 + c] = f2bf(acc[mt][reg]);
            pl[mt][reg] += alc * acc[mt][reg];
            pr[mt][reg] += arc * acc[mt][reg];
          }
        }
        if (ntl & 1){            // head h = ntl>>1 complete
          int h = ntl >> 1;
          #pragma unroll
          for (int mt = 0; mt < 2; ++mt){
            #pragma unroll
            for (int reg = 0; reg < 4; ++reg){
              float s0 = pl[mt][reg], s1 = pr[mt][reg];
              #pragma unroll
              for (int off = 1; off < 16; off <<= 1){
                s0 += __shfl_xor(s0, off, 64);
                s1 += __shfl_xor(s1, off, 64);
              }
              int rw = m0 + mt * 16 + quad * 4 + reg;
              if (mcol == 0 && rw < NNODES){
                h_l[rw * 4 + h] = s0;
                h_r[rw * 4 + h] = s1;
              }
              pl[mt][reg] = 0.f; pr[mt][reg] = 0.f;
            }
          }
        }
      } else {
        float rb = res_b[c];
        #pragma unroll
        for (int mt = 0; mt < 2; ++mt){
          #pragma unroll
          for (int reg = 0; reg < 4; ++reg){
            int rw = m0 + mt * 16 + quad * 4 + reg;
            if (rw < NNODES) outres[rw * 128 + c] = acc[mt][reg] + rb;
          }
        }
      }
    }
  }
}

// ---------------------------------------------------------------------------
// k_edgew: one lane per edge slot (wave per node, coalesced bucket access).
// wts4[slot] = bf16x4 of exp(leaky(h_l[r]+h_r[n]+he[t])) for the 4 heads.
// ---------------------------------------------------------------------------
__global__ __launch_bounds__(256) void k_edgew(const int* __restrict__ cnt,
    const int* __restrict__ rtp, const float* __restrict__ h_l,
    const float* __restrict__ h_r, const float* __restrict__ he_t_g,
    u16* __restrict__ wts4){
  __shared__ float he_s[NET * HEADS];
  if (threadIdx.x < NET * HEADS) he_s[threadIdx.x] = he_t_g[threadIdx.x];
  __syncthreads();
  const int n = blockIdx.x * 4 + (threadIdx.x >> 6);
  const int lane = threadIdx.x & 63;
  int deg = cnt[n]; if (deg > CAP) deg = CAP;
  if (lane >= deg) return;
  int sl = n * CAP + lane;
  int rt = rtp[sl];
  int r = rt & 0x1FFFF, t = rt >> 17;
  float4 hl = *(const float4*)&h_l[r * 4];
  float4 hr = *(const float4*)&h_r[n * 4];
  float4 he = *(const float4*)&he_s[t * 4];
  float x0 = hl.x + hr.x + he.x; x0 = x0 > 0.f ? x0 : NEG * x0;
  float x1 = hl.y + hr.y + he.y; x1 = x1 > 0.f ? x1 : NEG * x1;
  float x2 = hl.z + hr.z + he.z; x2 = x2 > 0.f ? x2 : NEG * x2;
  float x3 = hl.w + hr.w + he.w; x3 = x3 > 0.f ? x3 : NEG * x3;
  ushort4 w;
  w.x = f2bf(__expf(x0)); w.y = f2bf(__expf(x1));
  w.z = f2bf(__expf(x2)); w.w = f2bf(__expf(x3));
  *(ushort4*)&wts4[sl * 4] = w;
}

// ---------------------------------------------------------------------------
// k_nodeagg: one wave per node; half-wave per edge; ushort4 emb gather/lane.
// Inner loop: 3 independent loads (rtp, wts4, emb<-rtp). No exp, no h_l.
// Fused normalize + permute + fp32 residual (in out) + ELU.
// ---------------------------------------------------------------------------
__global__ __launch_bounds__(256) void k_nodeagg(const int* __restrict__ cnt,
    const int* __restrict__ rtp, const u16* __restrict__ wts4,
    const u16* __restrict__ emb, float* __restrict__ out){
  const int n = blockIdx.x * 4 + (threadIdx.x >> 6);   // grid*4 == NNODES exactly
  const int lane = threadIdx.x & 63;
  const int half = lane >> 5;
  const int L = lane & 31;             // dims L*4 .. L*4+3 (emb layout [head][32])
  const int h = L >> 3;
  int deg = cnt[n]; if (deg > CAP) deg = CAP;
  const int base = n * CAP;

  float a0 = 0.f, a1 = 0.f, a2 = 0.f, a3 = 0.f, ds = 0.f;
  for (int i = 0; i < deg; i += 2){
    int idx = i + half;
    bool valid = idx < deg;
    int sl = base + (valid ? idx : 0);
    int rt = rtp[sl];                              // broadcast (2 addrs/wave)
    uint2 wv = *(const uint2*)&wts4[sl * 4];       // broadcast 8B
    u32 word = (h & 2) ? wv.y : wv.x;
    u16 wh = (h & 1) ? (u16)(word >> 16) : (u16)(word & 0xFFFFu);
    float w = valid ? bf2f(wh) : 0.f;
    int r = rt & 0x1FFFF;
    ushort4 u = *(const ushort4*)&emb[r * 128 + L * 4];
    a0 += w * bf2f(u.x);
    a1 += w * bf2f(u.y);
    a2 += w * bf2f(u.z);
    a3 += w * bf2f(u.w);
    ds += w;
  }

  a0 += __shfl_xor(a0, 32, 64);
  a1 += __shfl_xor(a1, 32, 64);
  a2 += __shfl_xor(a2, 32, 64);
  a3 += __shfl_xor(a3, 32, 64);
  ds += __shfl_xor(ds, 32, 64);

  if (half == 0){
    float inv = (deg > 0) ? 1.f / ds : 0.f;
    // dim j = L*4+k -> out offset n*128 + (j&31)*4 + h = n*128 + (L&7)*16 + k*4 + h
    int ob = n * 128 + (L & 7) * 16 + h;
    float av[4] = {a0, a1, a2, a3};
    #pragma unroll
    for (int k = 0; k < 4; ++k){
      int o = ob + k * 4;
      float v = av[k] * inv + out[o];
      out[o] = v > 0.f ? v : (__expf(v) - 1.f);
    }
  }
}

// ---------------------------------------------------------------------------
extern "C" void kernel_launch(void* const* d_in, const int* in_sizes, int n_in,
                              void* d_out, int out_size, void* d_ws, size_t ws_size,
                              hipStream_t stream){
  const float* hmat     = (const float*)d_in[0];
  const int*   row      = (const int*)d_in[1];
  const int*   col      = (const int*)d_in[2];
  const int*   et       = (const int*)d_in[3];
  const float* edge_emb = (const float*)d_in[4];
  const float* W        = (const float*)d_in[5];
  const float* Wr       = (const float*)d_in[6];
  const float* a_l      = (const float*)d_in[7];
  const float* a_r      = (const float*)d_in[8];
  const float* a_e      = (const float*)d_in[9];
  const float* res_w    = (const float*)d_in[10];
  const float* res_b    = (const float*)d_in[11];
  float* out = (float*)d_out;

  char* ws = (char*)d_ws;
  // he_t 256 | Wt 64K | h_l 1.6M | h_r 1.6M | cnt 400K | rtp 25.6M |
  // wts4 51.2M | emb(bf16) 25.6M    (~106.1 MB)
  float* he_t   = (float*)(ws);
  u16*   Wt     = (u16*)  (ws + 256);
  float* h_l    = (float*)(ws + 65792);
  float* h_r    = (float*)(ws + 1665792);
  int*   cnt    = (int*)  (ws + 3265792);
  int*   rtp    = (int*)  (ws + 3665792);
  u16*   wts4   = (u16*)  (ws + 29265792);
  u16*   emb    = (u16*)  (ws + 80465792);

  hipLaunchKernelGGL(k_prep, dim3(129), dim3(256), 0, stream,
                     edge_emb, Wr, a_e, W, res_w, he_t, Wt, cnt);
  hipLaunchKernelGGL(k_scatter, dim3((NEDGES + 255) / 256), dim3(256), 0, stream,
                     row, col, et, cnt, rtp);
  hipLaunchKernelGGL(k_gemm2, dim3((NNODES + 127) / 128), dim3(256), 0, stream,
                     hmat, Wt, res_b, a_l, a_r, emb, out, h_l, h_r);
  hipLaunchKernelGGL(k_edgew, dim3(NNODES / 4), dim3(256), 0, stream,
                     cnt, rtp, h_l, h_r, he_t, wts4);
  hipLaunchKernelGGL(k_nodeagg, dim3(NNODES / 4), dim3(256), 0, stream,
                     cnt, rtp, wts4, emb, out);
}

// Round 9
// 398.151 us; speedup vs baseline: 1.0793x; 1.0793x over previous
//
#include <hip/hip_runtime.h>

#define NNODES 100000
#define NEDGES 1600000
#define INDIM 128
#define OUTD 32
#define HEADS 4
#define EDIM 32
#define NET 8
#define NEG 0.2f
#define CAP 64           // per-node bucket capacity (Poisson(16): P(>64) ~ 1e-20)
#define SB 1600          // scatter blocks (first in grid: latency overlaps gemm)
#define GB2 782          // gemm blocks: ceil(100000/128)

typedef unsigned short u16;
typedef unsigned int u32;
typedef __attribute__((ext_vector_type(8))) short bf16x8;
typedef __attribute__((ext_vector_type(4))) float f32x4;

__device__ __forceinline__ float bf2f(u16 u){ return __uint_as_float(((u32)u) << 16); }
__device__ __forceinline__ u16 f2bf(float f){
  u32 x = __float_as_uint(f);
  return (u16)((x + 0x7fffu + ((x >> 16) & 1u)) >> 16);   // RNE
}

// ---------------------------------------------------------------------------
// k_prep: block 0 -> he_t;  blocks 1..128 -> Wt transpose+cast;  all -> zero cnt
// ---------------------------------------------------------------------------
__global__ void k_prep(const float* __restrict__ edge_emb, const float* __restrict__ Wr,
                       const float* __restrict__ a_e, const float* __restrict__ W,
                       const float* __restrict__ res_w,
                       float* __restrict__ he_t, u16* __restrict__ Wt,
                       int* __restrict__ cnt){
  const int b = blockIdx.x, tid = threadIdx.x;
  for (int i = b * 256 + tid; i < NNODES; i += gridDim.x * 256) cnt[i] = 0;

  if (b == 0){
    __shared__ float sc[NET * 128];
    for (int idx = tid; idx < NET * 128; idx += 256){
      int t = idx >> 7, o = idx & 127;
      float s = 0.f;
      #pragma unroll
      for (int e = 0; e < EDIM; ++e)
        s += edge_emb[t * EDIM + e] * Wr[t * EDIM * 128 + e * 128 + o];
      sc[idx] = s * a_e[o];
    }
    __syncthreads();
    if (tid < NET * HEADS){
      int t = tid >> 2, h = tid & 3;
      float s = 0.f;
      #pragma unroll
      for (int d = 0; d < EDIM; ++d) s += sc[t * 128 + h * EDIM + d];
      he_t[tid] = s;
    }
  } else {
    int idx = (b - 1) * 256 + tid;     // 128 blocks cover 256*128
    int n = idx >> 7, k = idx & 127;
    float v = (n < 128) ? W[k * 128 + n] : res_w[k * 128 + (n - 128)];
    Wt[idx] = f2bf(v);
  }
}

// ---------------------------------------------------------------------------
// k_main: blocks [0,SB): bucket scatter rtp[c*CAP+pos] = row | etype<<17
//         blocks [SB,SB+GB2): MFMA GEMM, 128 rows x 256 cols, Wt in LDS.
//   gemm cols 0-127 -> emb bf16 + h_l/h_r; cols 128-255 -> d_out fp32 residual.
// ---------------------------------------------------------------------------
__global__ __launch_bounds__(256) void k_main(
    const float* __restrict__ hmat, const u16* __restrict__ Wt,
    const float* __restrict__ res_b, const float* __restrict__ a_l,
    const float* __restrict__ a_r, u16* __restrict__ emb, float* __restrict__ outres,
    float* __restrict__ h_l, float* __restrict__ h_r,
    const int* __restrict__ row, const int* __restrict__ col,
    const int* __restrict__ et, int* __restrict__ cnt, int* __restrict__ rtp){
  __shared__ u16 Wl[128 * 136];        // 34.8 KB (2-way bank spread = free)
  const int tid = threadIdx.x;

  if (blockIdx.x < SB){                // ---- scatter part ----
    for (int e = blockIdx.x * 256 + tid; e < NEDGES; e += SB * 256){
      int c = col[e];
      int pos = atomicAdd(&cnt[c], 1);
      if (pos < CAP) rtp[c * CAP + pos] = row[e] | (et[e] << 17);
    }
    return;
  }

  // ---- GEMM part ----
  const int gb = blockIdx.x - SB;
  const int wid = tid >> 6, lane = tid & 63;
  const int m0 = gb * 128 + wid * 32;
  const int mcol = lane & 15, quad = lane >> 4;

  // A fragments: 2 row-tiles x 4 k-steps, fp32 -> bf16 in-register
  bf16x8 A[2][4];
  #pragma unroll
  for (int mt = 0; mt < 2; ++mt){
    int r = m0 + mt * 16 + mcol;
    int rc = r < NNODES ? r : NNODES - 1;
    const float* hrow = &hmat[rc * 128 + quad * 8];
    #pragma unroll
    for (int ks = 0; ks < 4; ++ks){
      float4 a0 = *(const float4*)&hrow[ks * 32];
      float4 a1 = *(const float4*)&hrow[ks * 32 + 4];
      A[mt][ks][0] = (short)f2bf(a0.x); A[mt][ks][1] = (short)f2bf(a0.y);
      A[mt][ks][2] = (short)f2bf(a0.z); A[mt][ks][3] = (short)f2bf(a0.w);
      A[mt][ks][4] = (short)f2bf(a1.x); A[mt][ks][5] = (short)f2bf(a1.y);
      A[mt][ks][6] = (short)f2bf(a1.z); A[mt][ks][7] = (short)f2bf(a1.w);
    }
  }

  float pl[2][4] = {}, pr[2][4] = {};
  #pragma unroll
  for (int phase = 0; phase < 2; ++phase){
    if (phase) __syncthreads();
    // stage 128 rows of Wt (32 KB) -> LDS, 8 x 16B per thread
    #pragma unroll
    for (int j = 0; j < 8; ++j){
      int cid = tid + j * 256;          // 2048 chunks of ushort8
      int rowL = cid >> 4, k8 = cid & 15;
      *(uint4*)&Wl[rowL * 136 + k8 * 8] =
          *(const uint4*)&Wt[(phase * 128 + rowL) * 128 + k8 * 8];
    }
    __syncthreads();

    #pragma unroll
    for (int ntl = 0; ntl < 8; ++ntl){
      bf16x8 B[4];
      const u16* bp = &Wl[(ntl * 16 + mcol) * 136 + quad * 8];
      #pragma unroll
      for (int ks = 0; ks < 4; ++ks) B[ks] = *(const bf16x8*)&bp[ks * 32];

      f32x4 acc[2] = {{0.f,0.f,0.f,0.f},{0.f,0.f,0.f,0.f}};
      #pragma unroll
      for (int ks = 0; ks < 4; ++ks){
        acc[0] = __builtin_amdgcn_mfma_f32_16x16x32_bf16(A[0][ks], B[ks], acc[0], 0, 0, 0);
        acc[1] = __builtin_amdgcn_mfma_f32_16x16x32_bf16(A[1][ks], B[ks], acc[1], 0, 0, 0);
      }

      const int c = ntl * 16 + mcol;      // column within the 128-col phase
      if (phase == 0){
        float alc = a_l[c], arc = a_r[c];
        #pragma unroll
        for (int mt = 0; mt < 2; ++mt){
          #pragma unroll
          for (int reg = 0; reg < 4; ++reg){
            int rw = m0 + mt * 16 + quad * 4 + reg;
            if (rw < NNODES) emb[rw * 128 + c] = f2bf(acc[mt][reg]);
            pl[mt][reg] += alc * acc[mt][reg];
            pr[mt][reg] += arc * acc[mt][reg];
          }
        }
        if (ntl & 1){            // head h = ntl>>1 complete
          int h = ntl >> 1;
          #pragma unroll
          for (int mt = 0; mt < 2; ++mt){
            #pragma unroll
            for (int reg = 0; reg < 4; ++reg){
              float s0 = pl[mt][reg], s1 = pr[mt][reg];
              #pragma unroll
              for (int off = 1; off < 16; off <<= 1){
                s0 += __shfl_xor(s0, off, 64);
                s1 += __shfl_xor(s1, off, 64);
              }
              int rw = m0 + mt * 16 + quad * 4 + reg;
              if (mcol == 0 && rw < NNODES){
                h_l[rw * 4 + h] = s0;
                h_r[rw * 4 + h] = s1;
              }
              pl[mt][reg] = 0.f; pr[mt][reg] = 0.f;
            }
          }
        }
      } else {
        float rb = res_b[c];
        #pragma unroll
        for (int mt = 0; mt < 2; ++mt){
          #pragma unroll
          for (int reg = 0; reg < 4; ++reg){
            int rw = m0 + mt * 16 + quad * 4 + reg;
            if (rw < NNODES) outres[rw * 128 + c] = acc[mt][reg] + rb;
          }
        }
      }
    }
  }
}

// ---------------------------------------------------------------------------
// k_nodeagg: one wave per node.
// Prologue (lane = slot, parallel): w[4] = exp(leaky(h_l[r]+h_r[n]+he[t]))
//   -> LDS (fp32), r -> LDS.   (replaces the separate k_edgew kernel)
// Main loop (half-wave per edge, ushort4 emb gather per lane): LDS broadcast
//   reads only — no exp, no dependent global chain.
// Fused normalize + permute + fp32 residual (preloaded in out) + ELU.
// ---------------------------------------------------------------------------
__global__ __launch_bounds__(256) void k_nodeagg(const int* __restrict__ cnt,
    const int* __restrict__ rtp, const float* __restrict__ h_l,
    const float* __restrict__ h_r, const float* __restrict__ he_t_g,
    const u16* __restrict__ emb, float* __restrict__ out){
  __shared__ float he_s[NET * HEADS];
  __shared__ float wl[4][CAP][4];      // [wave][slot][head], fp32
  __shared__ int   rl[4][CAP];
  if (threadIdx.x < NET * HEADS) he_s[threadIdx.x] = he_t_g[threadIdx.x];
  __syncthreads();

  const int wid = threadIdx.x >> 6;
  const int n = blockIdx.x * 4 + wid;            // grid*4 == NNODES exactly
  const int lane = threadIdx.x & 63;
  int deg = cnt[n]; if (deg > CAP) deg = CAP;
  const int base = n * CAP;

  // ---- prologue: per-slot weights, all slots in parallel ----
  {
    bool v = lane < deg;
    int rt = rtp[base + (v ? lane : 0)];
    int r = rt & 0x1FFFF, t = (rt >> 17) & 7;
    float4 hl = *(const float4*)&h_l[r * 4];
    float4 hr = *(const float4*)&h_r[n * 4];
    float4 he = *(const float4*)&he_s[t * 4];
    float x0 = hl.x + hr.x + he.x; x0 = x0 > 0.f ? x0 : NEG * x0;
    float x1 = hl.y + hr.y + he.y; x1 = x1 > 0.f ? x1 : NEG * x1;
    float x2 = hl.z + hr.z + he.z; x2 = x2 > 0.f ? x2 : NEG * x2;
    float x3 = hl.w + hr.w + he.w; x3 = x3 > 0.f ? x3 : NEG * x3;
    float4 w4 = make_float4(__expf(x0), __expf(x1), __expf(x2), __expf(x3));
    *(float4*)&wl[wid][lane][0] = w4;
    rl[wid][lane] = r;
  }
  __syncthreads();

  const int half = lane >> 5;
  const int L = lane & 31;             // dims L*4 .. L*4+3 (emb layout [head][32])
  const int h = L >> 3;

  float a0 = 0.f, a1 = 0.f, a2 = 0.f, a3 = 0.f, ds = 0.f;
  for (int i = 0; i < deg; i += 2){
    int idx = i + half;
    bool valid = idx < deg;
    int ii = valid ? idx : 0;
    int r = rl[wid][ii];                         // LDS broadcast
    float w = valid ? wl[wid][ii][h] : 0.f;      // LDS broadcast (4 addrs/half)
    ushort4 u = *(const ushort4*)&emb[r * 128 + L * 4];
    a0 += w * bf2f(u.x);
    a1 += w * bf2f(u.y);
    a2 += w * bf2f(u.z);
    a3 += w * bf2f(u.w);
    ds += w;
  }

  a0 += __shfl_xor(a0, 32, 64);
  a1 += __shfl_xor(a1, 32, 64);
  a2 += __shfl_xor(a2, 32, 64);
  a3 += __shfl_xor(a3, 32, 64);
  ds += __shfl_xor(ds, 32, 64);

  if (half == 0){
    float inv = (deg > 0) ? 1.f / ds : 0.f;
    // dim j = L*4+k -> out offset n*128 + (j&31)*4 + h = n*128 + (L&7)*16 + k*4 + h
    int ob = n * 128 + (L & 7) * 16 + h;
    float av[4] = {a0, a1, a2, a3};
    #pragma unroll
    for (int k = 0; k < 4; ++k){
      int o = ob + k * 4;
      float v = av[k] * inv + out[o];
      out[o] = v > 0.f ? v : (__expf(v) - 1.f);
    }
  }
}

// ---------------------------------------------------------------------------
extern "C" void kernel_launch(void* const* d_in, const int* in_sizes, int n_in,
                              void* d_out, int out_size, void* d_ws, size_t ws_size,
                              hipStream_t stream){
  const float* hmat     = (const float*)d_in[0];
  const int*   row      = (const int*)d_in[1];
  const int*   col      = (const int*)d_in[2];
  const int*   et       = (const int*)d_in[3];
  const float* edge_emb = (const float*)d_in[4];
  const float* W        = (const float*)d_in[5];
  const float* Wr       = (const float*)d_in[6];
  const float* a_l      = (const float*)d_in[7];
  const float* a_r      = (const float*)d_in[8];
  const float* a_e      = (const float*)d_in[9];
  const float* res_w    = (const float*)d_in[10];
  const float* res_b    = (const float*)d_in[11];
  float* out = (float*)d_out;

  char* ws = (char*)d_ws;
  // he_t 256 | Wt 64K | h_l 1.6M | h_r 1.6M | cnt 400K | rtp 25.6M |
  // emb(bf16) 25.6M    (~55 MB)
  float* he_t   = (float*)(ws);
  u16*   Wt     = (u16*)  (ws + 256);
  float* h_l    = (float*)(ws + 65792);
  float* h_r    = (float*)(ws + 1665792);
  int*   cnt    = (int*)  (ws + 3265792);
  int*   rtp    = (int*)  (ws + 3665792);
  u16*   emb    = (u16*)  (ws + 29265792);

  hipLaunchKernelGGL(k_prep, dim3(129), dim3(256), 0, stream,
                     edge_emb, Wr, a_e, W, res_w, he_t, Wt, cnt);
  hipLaunchKernelGGL(k_main, dim3(SB + GB2), dim3(256), 0, stream,
                     hmat, Wt, res_b, a_l, a_r, emb, out, h_l, h_r,
                     row, col, et, cnt, rtp);
  hipLaunchKernelGGL(k_nodeagg, dim3(NNODES / 4), dim3(256), 0, stream,
                     cnt, rtp, h_l, h_r, he_t, emb, out);
}